// Round 6
// baseline (43.740 us; speedup 1.0000x reference)
//
#include <hip/hip_runtime.h>
#include <hip/hip_bf16.h>
#include <math.h>

#define D_MODEL 1024
#define LSEQ 2048
#define BATCH 2
#define NROWS (BATCH*LSEQ)   // 4096
#define NACT 8               // active decay chunks (A^256 underflows to 0 for observed A)
#define CHSL 32              // decay chunk length

typedef __bf16 bf16;
typedef __attribute__((ext_vector_type(8))) __bf16 bf16x8;
typedef __attribute__((ext_vector_type(4))) __bf16 bf16x4;
typedef __attribute__((ext_vector_type(4))) float f32x4;

__device__ __forceinline__ float sigA(float ap) {
    return fmaxf(1.0f / (1.0f + expf(-ap)), 1e-30f);
}

// async global->LDS, 16B/lane; LDS dest = wave-uniform base + lane*16
__device__ __forceinline__ void gload_lds16(const void* g, void* l) {
    __builtin_amdgcn_global_load_lds(
        (const __attribute__((address_space(1))) void*)g,
        (__attribute__((address_space(3))) void*)l, 16, 0, 0);
}

// ---------------- K1: merged W-cast (blocks 0..1023) + decay partial sums (blocks 1024..1087)
__global__ __launch_bounds__(256) void k_misc(const float* __restrict__ W, bf16* __restrict__ Wb,
                                              const float* __restrict__ x,
                                              const float* __restrict__ A_param,
                                              float* __restrict__ partial) {
    if (blockIdx.x < 1024) {                     // W f32 -> bf16
        int idx = (blockIdx.x * 256 + threadIdx.x) * 4;   // D*D = 1M
        f32x4 v = *reinterpret_cast<const f32x4*>(W + idx);
        bf16x4 o;
        #pragma unroll
        for (int k = 0; k < 4; ++k) o[k] = (bf16)v[k];
        *reinterpret_cast<bf16x4*>(Wb + idx) = o;
        return;
    }
    const int flat = blockIdx.x - 1024;          // 0..63
    const int c = flat & 7, dg = (flat >> 3) & 3, b = flat >> 5;
    const int d = dg * 256 + threadIdx.x;
    const float A = sigA(A_param[d]);
    const float l2A = log2f(A);
    const int s0 = c * CHSL;
    float w = exp2f((float)s0 * l2A);
    float sum = 0.0f;
    const int jmax = (c == NACT - 1) ? (LSEQ - s0) : CHSL;  // last chunk extends (safety for large A)
    if (w != 0.0f) {
        const float* xp = x + ((size_t)b * LSEQ + s0) * D_MODEL + d;
        for (int j0 = 0; j0 < jmax; j0 += 8) {
            if (w == 0.0f) break;
            #pragma unroll
            for (int j = 0; j < 8; ++j) {
                sum += w * xp[(size_t)(j0 + j) * D_MODEL];
                w *= A;
            }
        }
    }
    partial[((size_t)b * NACT + c) * D_MODEL + d] = sum;
}

// ---------------- K2: conv closed-form + skip + exact GELU -> bf16 G
__global__ __launch_bounds__(256) void k_prep(const float* __restrict__ x,
                                              const float* __restrict__ A_param,
                                              const float* __restrict__ Bv,
                                              const float* __restrict__ Cv,
                                              const float* __restrict__ Dv,
                                              const float* __restrict__ partial,
                                              bf16* __restrict__ G) {
    const int ib = blockIdx.x, b = blockIdx.z;   // grid (LSEQ/8, 1, BATCH) = 512 blocks
    const int i0 = ib * 8;
    const int d0 = threadIdx.x * 4;              // 256*4 = 1024 = D
    f32x4 P = {0.f, 0.f, 0.f, 0.f};
    #pragma unroll
    for (int c = 0; c < NACT; ++c)
        P += *reinterpret_cast<const f32x4*>(partial + ((size_t)b * NACT + c) * D_MODEL + d0);
    float A4[4], coeff[4], dvv[4], w[4];
    #pragma unroll
    for (int k = 0; k < 4; ++k) {
        A4[k] = sigA(A_param[d0 + k]);
        float l2 = log2f(A4[k]);
        coeff[k] = Cv[d0 + k] * Bv[d0 + k] * P[k];
        dvv[k] = Dv[d0 + k];
        w[k] = exp2f((float)(LSEQ - 1 - (i0 + 7)) * l2);   // conv(i) = coeff * A^(L-1-i)
    }
    for (int j = 7; j >= 0; --j) {
        const int i = i0 + j;
        f32x4 xv = *reinterpret_cast<const f32x4*>(x + ((size_t)b * LSEQ + i) * D_MODEL + d0);
        bf16x4 g;
        #pragma unroll
        for (int k = 0; k < 4; ++k) {
            float u = coeff[k] * w[k] + dvv[k] * xv[k];
            g[k] = (bf16)(0.5f * u * (1.0f + erff(u * 0.70710678118654752f)));
            w[k] *= A4[k];
        }
        *reinterpret_cast<bf16x4*>(G + ((size_t)b * LSEQ + i) * D_MODEL + d0) = g;
    }
}

// ---------------- K3: Z = bf16(G @ Wb^T + bias)
// TM=64 TN=128 BK=64, 128 threads = 2 waves, wave tile 64x64 (reads/MFMA = 0.5).
// LDS: 3 buffers x 24KB (A[64][64] + B[128][64] bf16), linear gload_lds dest.
// Involutive XOR swizzle within each 128B row: source byte 16*((lane&7)^(lane>>3))
// (coalescing preserved per 8-lane row-group); reads elem 8*((4ks+q)^(fr&7))
// -> conflict-free ds_read_b128.
// Counted vmcnt: depth-2 prefetch, 12 loads/wave/stage -> steady-state vmcnt(24).
__global__ __launch_bounds__(128) void k_gemm(const bf16* __restrict__ G,
                                              const bf16* __restrict__ Wb,
                                              const float* __restrict__ bias,
                                              bf16* __restrict__ Z) {
    __shared__ __align__(16) bf16 S[3 * 12288];   // 3 x 24KB = 72KB
    const int tid = threadIdx.x;
    const int lane = tid & 63, wave = tid >> 6;   // 2 waves
    const int bid = blockIdx.x;
    const int bx = (bid & 7) * 8 + ((bid >> 3) & 7);   // m-tile [0,64): XCD-chunked
    const int by = bid >> 6;                           // n-tile [0,8)
    const int row0 = bx * 64, col0 = by * 128;
    const int wc = wave;                          // wave tile 64x64: col half
    const int fr = lane & 15, q = lane >> 4;
    const int fx = fr & 7;
    f32x4 acc[4][4] = {};

    // staging: 24 chunks of 1KB (rows 0..63 = A from G, 64..191 = B from Wb);
    // wave owns chunks [wave*12, wave*12+12)
    const int lr8 = lane >> 3;
    const int sb = 16 * ((lane & 7) ^ lr8);       // swizzled source byte-in-row
    const bf16* srcbase[12];
    #pragma unroll
    for (int r = 0; r < 12; ++r) {
        const int c = wave * 12 + r;
        const bf16* mat;
        int row;
        if (c < 8) { mat = G;  row = row0 + c * 8 + lr8; }
        else       { mat = Wb; row = col0 + (c - 8) * 8 + lr8; }
        srcbase[r] = (const bf16*)((const char*)(mat + (size_t)row * D_MODEL) + sb);
    }

    auto stage = [&](int buf, int k0) {
        #pragma unroll
        for (int r = 0; r < 12; ++r)
            gload_lds16(srcbase[r] + k0, &S[buf * 12288 + (wave * 12 + r) * 512]);
    };

    stage(0, 0);
    stage(1, 64);
    for (int t = 0; t < 16; ++t) {
        const int cur = t % 3;
        if (t + 2 < 16) stage((t + 2) % 3, (t + 2) * 64);
        __builtin_amdgcn_sched_barrier(0);
        if (t < 14)       asm volatile("s_waitcnt vmcnt(24)" ::: "memory");
        else if (t == 14) asm volatile("s_waitcnt vmcnt(12)" ::: "memory");
        else              asm volatile("s_waitcnt vmcnt(0)"  ::: "memory");
        __builtin_amdgcn_s_barrier();
        __builtin_amdgcn_sched_barrier(0);
        const bf16* SA = &S[cur * 12288];
        const bf16* SB = SA + 4096;
        bf16x8 a[4][2], bb[4][2];
        #pragma unroll
        for (int fm = 0; fm < 4; ++fm)
            #pragma unroll
            for (int ks = 0; ks < 2; ++ks)
                a[fm][ks] = *reinterpret_cast<const bf16x8*>(
                    SA + (fm * 16 + fr) * 64 + 8 * ((4 * ks + q) ^ fx));
        #pragma unroll
        for (int fn = 0; fn < 4; ++fn)
            #pragma unroll
            for (int ks = 0; ks < 2; ++ks)
                bb[fn][ks] = *reinterpret_cast<const bf16x8*>(
                    SB + (wc * 64 + fn * 16 + fr) * 64 + 8 * ((4 * ks + q) ^ fx));
        #pragma unroll
        for (int fm = 0; fm < 4; ++fm)
            #pragma unroll
            for (int fn = 0; fn < 4; ++fn)
                #pragma unroll
                for (int ks = 0; ks < 2; ++ks)
                    acc[fm][fn] = __builtin_amdgcn_mfma_f32_16x16x32_bf16(a[fm][ks], bb[fn][ks], acc[fm][fn], 0, 0, 0);
        __builtin_amdgcn_sched_barrier(0);
        __builtin_amdgcn_s_barrier();   // reads of buf t done before it is restaged
    }
    // epilogue: C/D layout col = lane&15, row = (lane>>4)*4 + reg; +bias, emit bf16
    #pragma unroll
    for (int fm = 0; fm < 4; ++fm) {
        const int rbase = row0 + fm * 16 + (lane >> 4) * 4;
        #pragma unroll
        for (int fn = 0; fn < 4; ++fn) {
            const int c = col0 + wc * 64 + fn * 16 + fr;
            const float bv = bias[c];
            #pragma unroll
            for (int r = 0; r < 4; ++r)
                Z[(size_t)(rbase + r) * D_MODEL + c] = (bf16)(acc[fm][fn][r] + bv);
        }
    }
}

// ---------------- K4: out = LayerNorm(x + Z) * gamma + beta
__global__ __launch_bounds__(256) void k_ln(const bf16* __restrict__ Z,
                                            const float* __restrict__ x,
                                            const float* __restrict__ gamma,
                                            const float* __restrict__ beta,
                                            float* __restrict__ out) {
    const int row = blockIdx.x;
    const int t = threadIdx.x;
    bf16x4 zv = *reinterpret_cast<const bf16x4*>(Z + (size_t)row * D_MODEL + t * 4);
    f32x4 xv = *reinterpret_cast<const f32x4*>(x + (size_t)row * D_MODEL + t * 4);
    float z[4];
    float s = 0.0f, sq = 0.0f;
    #pragma unroll
    for (int k = 0; k < 4; ++k) {
        z[k] = xv[k] + (float)zv[k];
        s += z[k]; sq += z[k] * z[k];
    }
    #pragma unroll
    for (int o = 1; o < 64; o <<= 1) { s += __shfl_xor(s, o, 64); sq += __shfl_xor(sq, o, 64); }
    __shared__ float ls[4], lq[4];
    const int wave = t >> 6;
    if ((t & 63) == 0) { ls[wave] = s; lq[wave] = sq; }
    __syncthreads();
    s = ls[0] + ls[1] + ls[2] + ls[3];
    sq = lq[0] + lq[1] + lq[2] + lq[3];
    const float mu = s * (1.0f / D_MODEL);
    const float var = sq * (1.0f / D_MODEL) - mu * mu;
    const float inv = rsqrtf(var + 1e-5f);
    f32x4 g = *reinterpret_cast<const f32x4*>(gamma + t * 4);
    f32x4 be = *reinterpret_cast<const f32x4*>(beta + t * 4);
    f32x4 o;
    #pragma unroll
    for (int k = 0; k < 4; ++k) o[k] = (z[k] - mu) * inv * g[k] + be[k];
    *reinterpret_cast<f32x4*>(out + (size_t)row * D_MODEL + t * 4) = o;
}

extern "C" void kernel_launch(void* const* d_in, const int* in_sizes, int n_in,
                              void* d_out, int out_size, void* d_ws, size_t ws_size,
                              hipStream_t stream) {
    const float* x       = (const float*)d_in[0];
    const float* A_param = (const float*)d_in[1];
    const float* B_vec   = (const float*)d_in[2];
    const float* C_vec   = (const float*)d_in[3];
    const float* D_vec   = (const float*)d_in[4];
    const float* W       = (const float*)d_in[5];
    const float* b_proj  = (const float*)d_in[6];
    const float* gamma   = (const float*)d_in[7];
    const float* beta    = (const float*)d_in[8];
    float* out = (float*)d_out;

    char* ws = (char*)d_ws;
    float* partial = (float*)ws;                                  // 64 KiB
    bf16*  Wb      = (bf16*)(ws + (128 << 10));                   // 2 MiB
    bf16*  G       = (bf16*)(ws + (128 << 10) + (2 << 20));       // 8 MiB
    bf16*  Z       = (bf16*)(ws + (128 << 10) + (10 << 20));      // 8 MiB

    hipLaunchKernelGGL(k_misc, dim3(1088), dim3(256), 0, stream, W, Wb, x, A_param, partial);
    hipLaunchKernelGGL(k_prep, dim3(LSEQ / 8, 1, BATCH), dim3(256), 0, stream,
                       x, A_param, B_vec, C_vec, D_vec, partial, G);
    hipLaunchKernelGGL(k_gemm, dim3(512), dim3(128), 0, stream, G, Wb, b_proj, Z);
    hipLaunchKernelGGL(k_ln,   dim3(NROWS), dim3(256), 0, stream, Z, x, gamma, beta, out);
}

// Round 7
// 41.062 us; speedup vs baseline: 1.0652x; 1.0652x over previous
//
#include <hip/hip_runtime.h>
#include <hip/hip_bf16.h>
#include <math.h>

#define D_MODEL 1024
#define LSEQ 2048
#define BATCH 2
#define NROWS (BATCH*LSEQ)   // 4096
#define NACT 8               // active decay chunks (A^256 underflows to 0 for observed A)
#define CHSL 32              // decay chunk length

typedef __bf16 bf16;
typedef __attribute__((ext_vector_type(8))) __bf16 bf16x8;
typedef __attribute__((ext_vector_type(4))) __bf16 bf16x4;
typedef __attribute__((ext_vector_type(4))) float f32x4;

__device__ __forceinline__ float sigA(float ap) {
    return fmaxf(1.0f / (1.0f + expf(-ap)), 1e-30f);
}

// async global->LDS, 16B/lane; LDS dest = wave-uniform base + lane*16
__device__ __forceinline__ void gload_lds16(const void* g, void* l) {
    __builtin_amdgcn_global_load_lds(
        (const __attribute__((address_space(1))) void*)g,
        (__attribute__((address_space(3))) void*)l, 16, 0, 0);
}

// ---------------- K1: merged W-cast (blocks 0..1023) + decay partial sums (blocks 1024..1087)
__global__ __launch_bounds__(256) void k_misc(const float* __restrict__ W, bf16* __restrict__ Wb,
                                              const float* __restrict__ x,
                                              const float* __restrict__ A_param,
                                              float* __restrict__ partial) {
    if (blockIdx.x < 1024) {                     // W f32 -> bf16
        int idx = (blockIdx.x * 256 + threadIdx.x) * 4;   // D*D = 1M
        f32x4 v = *reinterpret_cast<const f32x4*>(W + idx);
        bf16x4 o;
        #pragma unroll
        for (int k = 0; k < 4; ++k) o[k] = (bf16)v[k];
        *reinterpret_cast<bf16x4*>(Wb + idx) = o;
        return;
    }
    const int flat = blockIdx.x - 1024;          // 0..63
    const int c = flat & 7, dg = (flat >> 3) & 3, b = flat >> 5;
    const int d = dg * 256 + threadIdx.x;
    const float A = sigA(A_param[d]);
    const float l2A = log2f(A);
    const int s0 = c * CHSL;
    float w = exp2f((float)s0 * l2A);
    float sum = 0.0f;
    const int jmax = (c == NACT - 1) ? (LSEQ - s0) : CHSL;  // last chunk extends (safety for large A)
    if (w != 0.0f) {
        const float* xp = x + ((size_t)b * LSEQ + s0) * D_MODEL + d;
        for (int j0 = 0; j0 < jmax; j0 += 8) {
            if (w == 0.0f) break;
            #pragma unroll
            for (int j = 0; j < 8; ++j) {
                sum += w * xp[(size_t)(j0 + j) * D_MODEL];
                w *= A;
            }
        }
    }
    partial[((size_t)b * NACT + c) * D_MODEL + d] = sum;
}

// ---------------- K2: conv closed-form + skip + exact GELU -> bf16 G
__global__ __launch_bounds__(256) void k_prep(const float* __restrict__ x,
                                              const float* __restrict__ A_param,
                                              const float* __restrict__ Bv,
                                              const float* __restrict__ Cv,
                                              const float* __restrict__ Dv,
                                              const float* __restrict__ partial,
                                              bf16* __restrict__ G) {
    const int ib = blockIdx.x, b = blockIdx.z;   // grid (LSEQ/8, 1, BATCH) = 512 blocks
    const int i0 = ib * 8;
    const int d0 = threadIdx.x * 4;              // 256*4 = 1024 = D
    f32x4 P = {0.f, 0.f, 0.f, 0.f};
    #pragma unroll
    for (int c = 0; c < NACT; ++c)
        P += *reinterpret_cast<const f32x4*>(partial + ((size_t)b * NACT + c) * D_MODEL + d0);
    float A4[4], coeff[4], dvv[4], w[4];
    #pragma unroll
    for (int k = 0; k < 4; ++k) {
        A4[k] = sigA(A_param[d0 + k]);
        float l2 = log2f(A4[k]);
        coeff[k] = Cv[d0 + k] * Bv[d0 + k] * P[k];
        dvv[k] = Dv[d0 + k];
        w[k] = exp2f((float)(LSEQ - 1 - (i0 + 7)) * l2);   // conv(i) = coeff * A^(L-1-i)
    }
    for (int j = 7; j >= 0; --j) {
        const int i = i0 + j;
        f32x4 xv = *reinterpret_cast<const f32x4*>(x + ((size_t)b * LSEQ + i) * D_MODEL + d0);
        bf16x4 g;
        #pragma unroll
        for (int k = 0; k < 4; ++k) {
            float u = coeff[k] * w[k] + dvv[k] * xv[k];
            g[k] = (bf16)(0.5f * u * (1.0f + erff(u * 0.70710678118654752f)));
            w[k] *= A4[k];
        }
        *reinterpret_cast<bf16x4*>(G + ((size_t)b * LSEQ + i) * D_MODEL + d0) = g;
    }
}

// ---------------- K3: Z = bf16(G @ Wb^T + bias)
// TM=64 TN=128 BK=64, 4 waves (wave tile 32x64), 512 blocks, 3 LDS buffers (72KB).
// Register-fragment double-buffer pipeline, ONE barrier per K-step:
//   stage(t+2) ; lgkmcnt(0) [drain frags[t] + buffer-reuse safety] ;
//   vmcnt(6)  [certify tile t+1] ; s_barrier ;
//   ds_read frags[t+1] (overlaps MFMA) ; setprio(1) MFMA(frags[t]) setprio(0)
// Involutive XOR swizzle within each 128B row: source byte 16*((lane&7)^(lane>>3)),
// read elem 8*((4ks+q)^(fr&7)) -> conflict-free ds_read_b128, coalescing preserved.
__global__ __launch_bounds__(256) void k_gemm(const bf16* __restrict__ G,
                                              const bf16* __restrict__ Wb,
                                              const float* __restrict__ bias,
                                              bf16* __restrict__ Z) {
    __shared__ __align__(16) bf16 S[3 * 12288];   // 3 x 24KB = 72KB
    const int tid = threadIdx.x;
    const int lane = tid & 63, wave = tid >> 6;
    const int bid = blockIdx.x;
    const int bx = (bid & 7) * 8 + ((bid >> 3) & 7);   // m-tile [0,64): XCD-chunked
    const int by = bid >> 6;                           // n-tile [0,8)
    const int row0 = bx * 64, col0 = by * 128;
    const int wr = wave >> 1, wc = wave & 1;      // wave tile 32x64
    const int fr = lane & 15, q = lane >> 4;
    const int fx = fr & 7;
    f32x4 acc[2][4] = {};

    // staging: 24 chunks of 1KB (rows 0..63 = A from G, 64..191 = B from Wb);
    // wave owns chunks [wave*6, wave*6+6)
    const int lr8 = lane >> 3;
    const int sb = 16 * ((lane & 7) ^ lr8);       // swizzled source byte-in-row
    const bf16* srcbase[6];
    #pragma unroll
    for (int r = 0; r < 6; ++r) {
        const int c = wave * 6 + r;
        const bf16* mat;
        int row;
        if (c < 8) { mat = G;  row = row0 + c * 8 + lr8; }
        else       { mat = Wb; row = col0 + (c - 8) * 8 + lr8; }
        srcbase[r] = (const bf16*)((const char*)(mat + (size_t)row * D_MODEL) + sb);
    }

    auto stage = [&](int buf, int k0) {
        #pragma unroll
        for (int r = 0; r < 6; ++r)
            gload_lds16(srcbase[r] + k0, &S[buf * 12288 + (wave * 6 + r) * 512]);
    };

    bf16x8 aE[2][2], bE[4][2], aO[2][2], bO[4][2];

    auto readFrags = [&](int bufI, bf16x8 (&a)[2][2], bf16x8 (&bb)[4][2]) {
        const bf16* SA = &S[bufI * 12288];
        const bf16* SB = SA + 4096;
        #pragma unroll
        for (int fm = 0; fm < 2; ++fm)
            #pragma unroll
            for (int ks = 0; ks < 2; ++ks)
                a[fm][ks] = *reinterpret_cast<const bf16x8*>(
                    SA + (wr * 32 + fm * 16 + fr) * 64 + 8 * ((4 * ks + q) ^ fx));
        #pragma unroll
        for (int fn = 0; fn < 4; ++fn)
            #pragma unroll
            for (int ks = 0; ks < 2; ++ks)
                bb[fn][ks] = *reinterpret_cast<const bf16x8*>(
                    SB + (wc * 64 + fn * 16 + fr) * 64 + 8 * ((4 * ks + q) ^ fx));
    };

    auto mfmaAll = [&](bf16x8 (&a)[2][2], bf16x8 (&bb)[4][2]) {
        __builtin_amdgcn_s_setprio(1);
        #pragma unroll
        for (int fm = 0; fm < 2; ++fm)
            #pragma unroll
            for (int fn = 0; fn < 4; ++fn)
                #pragma unroll
                for (int ks = 0; ks < 2; ++ks)
                    acc[fm][fn] = __builtin_amdgcn_mfma_f32_16x16x32_bf16(a[fm][ks], bb[fn][ks], acc[fm][fn], 0, 0, 0);
        __builtin_amdgcn_s_setprio(0);
    };

    // prologue: stage tiles 0,1; certify tile 0; read frags[0] into E
    stage(0, 0);
    stage(1, 64);
    asm volatile("s_waitcnt vmcnt(6)" ::: "memory");   // tile0 landed (tile1 in flight)
    __builtin_amdgcn_s_barrier();
    __builtin_amdgcn_sched_barrier(0);
    readFrags(0, aE, bE);

    #define ITER_BODY(T, ACUR, BCUR, ANXT, BNXT)                                   \
    {                                                                              \
        if ((T) + 2 < 16) stage(((T) + 2) % 3, ((T) + 2) * 64);                    \
        __builtin_amdgcn_sched_barrier(0);                                         \
        asm volatile("s_waitcnt lgkmcnt(0)" ::: "memory");                         \
        if ((T) + 2 < 16)      asm volatile("s_waitcnt vmcnt(6)" ::: "memory");    \
        else if ((T) + 1 < 16) asm volatile("s_waitcnt vmcnt(0)" ::: "memory");    \
        __builtin_amdgcn_sched_barrier(0);                                         \
        __builtin_amdgcn_s_barrier();                                              \
        __builtin_amdgcn_sched_barrier(0);                                         \
        if ((T) + 1 < 16) readFrags(((T) + 1) % 3, ANXT, BNXT);                    \
        mfmaAll(ACUR, BCUR);                                                       \
    }

    #pragma unroll
    for (int tt = 0; tt < 16; tt += 2) {
        ITER_BODY(tt, aE, bE, aO, bO);
        ITER_BODY(tt + 1, aO, bO, aE, bE);
    }
    #undef ITER_BODY

    // epilogue: C/D layout col = lane&15, row = (lane>>4)*4 + reg; +bias, emit bf16
    #pragma unroll
    for (int fm = 0; fm < 2; ++fm) {
        const int rbase = row0 + wr * 32 + fm * 16 + (lane >> 4) * 4;
        #pragma unroll
        for (int fn = 0; fn < 4; ++fn) {
            const int c = col0 + wc * 64 + fn * 16 + fr;
            const float bv = bias[c];
            #pragma unroll
            for (int r = 0; r < 4; ++r)
                Z[(size_t)(rbase + r) * D_MODEL + c] = (bf16)(acc[fm][fn][r] + bv);
        }
    }
}

// ---------------- K4: out = LayerNorm(x + Z) * gamma + beta
__global__ __launch_bounds__(256) void k_ln(const bf16* __restrict__ Z,
                                            const float* __restrict__ x,
                                            const float* __restrict__ gamma,
                                            const float* __restrict__ beta,
                                            float* __restrict__ out) {
    const int row = blockIdx.x;
    const int t = threadIdx.x;
    bf16x4 zv = *reinterpret_cast<const bf16x4*>(Z + (size_t)row * D_MODEL + t * 4);
    f32x4 xv = *reinterpret_cast<const f32x4*>(x + (size_t)row * D_MODEL + t * 4);
    float z[4];
    float s = 0.0f, sq = 0.0f;
    #pragma unroll
    for (int k = 0; k < 4; ++k) {
        z[k] = xv[k] + (float)zv[k];
        s += z[k]; sq += z[k] * z[k];
    }
    #pragma unroll
    for (int o = 1; o < 64; o <<= 1) { s += __shfl_xor(s, o, 64); sq += __shfl_xor(sq, o, 64); }
    __shared__ float ls[4], lq[4];
    const int wave = t >> 6;
    if ((t & 63) == 0) { ls[wave] = s; lq[wave] = sq; }
    __syncthreads();
    s = ls[0] + ls[1] + ls[2] + ls[3];
    sq = lq[0] + lq[1] + lq[2] + lq[3];
    const float mu = s * (1.0f / D_MODEL);
    const float var = sq * (1.0f / D_MODEL) - mu * mu;
    const float inv = rsqrtf(var + 1e-5f);
    f32x4 g = *reinterpret_cast<const f32x4*>(gamma + t * 4);
    f32x4 be = *reinterpret_cast<const f32x4*>(beta + t * 4);
    f32x4 o;
    #pragma unroll
    for (int k = 0; k < 4; ++k) o[k] = (z[k] - mu) * inv * g[k] + be[k];
    *reinterpret_cast<f32x4*>(out + (size_t)row * D_MODEL + t * 4) = o;
}

extern "C" void kernel_launch(void* const* d_in, const int* in_sizes, int n_in,
                              void* d_out, int out_size, void* d_ws, size_t ws_size,
                              hipStream_t stream) {
    const float* x       = (const float*)d_in[0];
    const float* A_param = (const float*)d_in[1];
    const float* B_vec   = (const float*)d_in[2];
    const float* C_vec   = (const float*)d_in[3];
    const float* D_vec   = (const float*)d_in[4];
    const float* W       = (const float*)d_in[5];
    const float* b_proj  = (const float*)d_in[6];
    const float* gamma   = (const float*)d_in[7];
    const float* beta    = (const float*)d_in[8];
    float* out = (float*)d_out;

    char* ws = (char*)d_ws;
    float* partial = (float*)ws;                                  // 64 KiB
    bf16*  Wb      = (bf16*)(ws + (128 << 10));                   // 2 MiB
    bf16*  G       = (bf16*)(ws + (128 << 10) + (2 << 20));       // 8 MiB
    bf16*  Z       = (bf16*)(ws + (128 << 10) + (10 << 20));      // 8 MiB

    hipLaunchKernelGGL(k_misc, dim3(1088), dim3(256), 0, stream, W, Wb, x, A_param, partial);
    hipLaunchKernelGGL(k_prep, dim3(LSEQ / 8, 1, BATCH), dim3(256), 0, stream,
                       x, A_param, B_vec, C_vec, D_vec, partial, G);
    hipLaunchKernelGGL(k_gemm, dim3(512), dim3(256), 0, stream, G, Wb, b_proj, Z);
    hipLaunchKernelGGL(k_ln,   dim3(NROWS), dim3(256), 0, stream, Z, x, gamma, beta, out);
}